// Round 12
// baseline (241.158 us; speedup 1.0000x reference)
//
#include <hip/hip_runtime.h>
#include <hip/hip_bf16.h>
#include <math.h>

#define Bb 16
#define Tt 64
#define Ff 64
#define MAXE 2048

// ---------------- kprep: block 0 = CSR build; block 1 = weight tables -------
__global__ __launch_bounds__(256) void kprep(
    const int* __restrict__ src, const int* __restrict__ dst, int E,
    const float* __restrict__ W_enc, const float* __restrict__ b_enc,
    const float* __restrict__ W_gat, const float* __restrict__ attn_l,
    const float* __restrict__ attn_r, const float* __restrict__ b_gat,
    int* __restrict__ off, int* __restrict__ csr,
    float* __restrict__ A, float* __restrict__ Bc,
    float* __restrict__ aA, float* __restrict__ aB,
    float* __restrict__ rA, float* __restrict__ rB) {
  __shared__ int s_src[MAXE], s_dst[MAXE];
  __shared__ int cnt[Ff], base[Ff];
  __shared__ __align__(16) float We[64][64], Be[64][64], Wg[64][64];
  __shared__ __align__(16) float As[64][64], Bs[64][64];
  __shared__ float al_s[64], ar_s[64], bg_s[64];
  int t = threadIdx.x;

  if (blockIdx.x == 0) {                       // ---- CSR by dst ----
    for (int e = t; e < E; e += 256) { s_src[e] = src[e]; s_dst[e] = dst[e]; }
    if (t < Ff) cnt[t] = 0;
    __syncthreads();
    for (int e = t; e < E; e += 256) atomicAdd(&cnt[s_dst[e]], 1);
    __syncthreads();
    if (t == 0) {
      int s = 0;
      for (int i = 0; i < Ff; ++i) { base[i] = s; off[i] = s; s += cnt[i]; }
      off[Ff] = s;
    }
    __syncthreads();
    if (t < Ff) {
      int pos = base[t];
      for (int e = 0; e < E; ++e)
        if (s_dst[e] == t) csr[pos++] = s_src[e];
    }
    return;
  }

  // ---- tables: A = We@Wg, Bc = Be@Wg (+b_gat), attn scalar tables ----
  for (int i = t; i < 1024; i += 256) {
    ((float4*)We)[i] = ((const float4*)W_enc)[i];
    ((float4*)Be)[i] = ((const float4*)b_enc)[i];
    ((float4*)Wg)[i] = ((const float4*)W_gat)[i];
  }
  if (t < 64) { al_s[t] = attn_l[t]; ar_s[t] = attn_r[t]; bg_s[t] = b_gat[t]; }
  __syncthreads();
  int n = t >> 2, q = t & 3;
  float accA[16], accB[16];
#pragma unroll
  for (int j = 0; j < 16; ++j) { accA[j] = 0.f; accB[j] = 0.f; }
  for (int k = 0; k < 64; ++k) {
    float we = We[n][k], be = Be[n][k];
#pragma unroll
    for (int c = 0; c < 4; ++c) {
      float4 wg = *(const float4*)&Wg[k][q * 16 + c * 4];
      accA[c*4+0] = fmaf(we, wg.x, accA[c*4+0]); accB[c*4+0] = fmaf(be, wg.x, accB[c*4+0]);
      accA[c*4+1] = fmaf(we, wg.y, accA[c*4+1]); accB[c*4+1] = fmaf(be, wg.y, accB[c*4+1]);
      accA[c*4+2] = fmaf(we, wg.z, accA[c*4+2]); accB[c*4+2] = fmaf(be, wg.z, accB[c*4+2]);
      accA[c*4+3] = fmaf(we, wg.w, accA[c*4+3]); accB[c*4+3] = fmaf(be, wg.w, accB[c*4+3]);
    }
  }
#pragma unroll
  for (int c = 0; c < 4; ++c) {
    float4 va, vb, vbg;
    va.x = accA[c*4+0]; va.y = accA[c*4+1]; va.z = accA[c*4+2]; va.w = accA[c*4+3];
    vb.x = accB[c*4+0]; vb.y = accB[c*4+1]; vb.z = accB[c*4+2]; vb.w = accB[c*4+3];
    vbg.x = vb.x + bg_s[q*16+c*4+0]; vbg.y = vb.y + bg_s[q*16+c*4+1];
    vbg.z = vb.z + bg_s[q*16+c*4+2]; vbg.w = vb.w + bg_s[q*16+c*4+3];
    *(float4*)&As[n][q*16 + c*4] = va;
    *(float4*)&Bs[n][q*16 + c*4] = vb;       // unfolded (attn tables)
    *(float4*)&A[n*64 + q*16 + c*4] = va;
    *(float4*)&Bc[n*64 + q*16 + c*4] = vbg;  // folded (+b_gat; sum(alpha)=1 => exact)
  }
  __syncthreads();
  float sa = 0.f, sb = 0.f, sra = 0.f, srb = 0.f;
#pragma unroll
  for (int j = 0; j < 16; ++j) {
    float alv = al_s[q*16 + j], arv = ar_s[q*16 + j];
    float av = As[n][q*16 + j], bv = Bs[n][q*16 + j];
    sa  = fmaf(av, alv, sa);  sb  = fmaf(bv, alv, sb);
    sra = fmaf(av, arv, sra); srb = fmaf(bv, arv, srb);
  }
  aA[t] = sa; aB[t] = sb; rA[t] = sra; rB[t] = srb;
}

// ---------------- k_gat: per (b,t); feat staged in LDS once ----------------
__global__ __launch_bounds__(256) void k_gat(
    const float* __restrict__ hist, const float* __restrict__ Ag,
    const float* __restrict__ Bg, const float* __restrict__ aAg,
    const float* __restrict__ aBg, const float* __restrict__ rAg,
    const float* __restrict__ rBg, const int* __restrict__ off,
    const int* __restrict__ csr, int E, float* __restrict__ g_out) {
  __shared__ __align__(16) float feat[64 * 68];   // feat' = x*A + Bc (padded rows)
  __shared__ float x_s[64];
  __shared__ float el_s[64][4], er_s[64][4];
  __shared__ int csr_s[1152];
  __shared__ int off_s[Ff + 1];
  int bt = blockIdx.x, t = threadIdx.x;
  if (t < 64) x_s[t] = hist[bt * 64 + t];
  if (t < Ff + 1) off_s[t] = off[t];
  for (int e = t; e < E; e += 256) csr_s[e] = csr[e];
  __syncthreads();

  // ---- stage feat: thread (s, q) -> feat[s][q*16..+15]; coalesced A/Bc ----
  int s0 = t >> 2, q = t & 3;
  {
    float xs = x_s[s0];
    const float4* Ar = (const float4*)(Ag + (s0 << 6) + (q << 4));
    const float4* Br = (const float4*)(Bg + (s0 << 6) + (q << 4));
#pragma unroll
    for (int c = 0; c < 4; ++c) {
      float4 a4 = Ar[c], b4 = Br[c];
      float4 o;
      o.x = fmaf(xs, a4.x, b4.x); o.y = fmaf(xs, a4.y, b4.y);
      o.z = fmaf(xs, a4.z, b4.z); o.w = fmaf(xs, a4.w, b4.w);
      *(float4*)&feat[s0 * 68 + (q << 4) + (c << 2)] = o;
    }
    el_s[s0][q] = fmaf(xs, aAg[t], aBg[t]);
    er_s[s0][q] = fmaf(xs, rAg[t], rBg[t]);
  }
  __syncthreads();

  // ---- edge phase: thread (d, hd); feat from LDS ----
  int d = s0, hd = q;
  int o0 = off_s[d], o1 = off_s[d + 1];
  float erd = er_s[d][hd];
  float den = 0.f;
  float acc[16];
#pragma unroll
  for (int j = 0; j < 16; ++j) acc[j] = 0.f;
  for (int e = o0; e < o1; ++e) {
    int s = csr_s[e];
    float ee = el_s[s][hd] + erd;
    ee = fmaxf(ee, 0.2f * ee);
    float p = __expf(ee);               // no max-shift: |e| bounded, exact alpha
    den += p;
    const float* fr = &feat[s * 68 + (hd << 4)];
#pragma unroll
    for (int c = 0; c < 4; ++c) {
      float4 fv = *(const float4*)&fr[c << 2];
      acc[c*4+0] = fmaf(p, fv.x, acc[c*4+0]);
      acc[c*4+1] = fmaf(p, fv.y, acc[c*4+1]);
      acc[c*4+2] = fmaf(p, fv.z, acc[c*4+2]);
      acc[c*4+3] = fmaf(p, fv.w, acc[c*4+3]);
    }
  }
  float inv = __builtin_amdgcn_rcpf(den);
  float* gp = g_out + (size_t)bt * 4096 + (d << 6) + (hd << 4);
#pragma unroll
  for (int c = 0; c < 4; ++c) {
    float4 o;
    o.x = acc[c*4+0] * inv; o.y = acc[c*4+1] * inv;
    o.z = acc[c*4+2] * inv; o.w = acc[c*4+3] * inv;
    *(float4*)&gp[c << 2] = o;
  }
}

// ---- k_gru: per (f,b); all-g staged; phase A pipelined into serial loop ----
__device__ __forceinline__ float qsum(float v) {
  v += __int_as_float(__builtin_amdgcn_mov_dpp(__float_as_int(v), 0xB1, 0xF, 0xF, true));
  v += __int_as_float(__builtin_amdgcn_mov_dpp(__float_as_int(v), 0x4E, 0xF, 0xF, true));
  return v;
}

__global__ __launch_bounds__(256, 4) void k_gru(
    const float* __restrict__ W_ih, const float* __restrict__ W_hh,
    const float* __restrict__ b_ih, const float* __restrict__ b_hh,
    const float* __restrict__ W_dec, const float* __restrict__ b_dec,
    float* __restrict__ hid, float* __restrict__ ans) {
  __shared__ __align__(16) float g_all[64 * 68];      // all 64 g rows (17.4 KB)
  __shared__ __align__(16) float4 xw4[16 * 64];       // [st][row] {xr,xz,xn,-} (16 KB)
  __shared__ __align__(16) float h_s[2][64];
  __shared__ __align__(16) float hbuf[2][8][64];
  int blk = blockIdx.x;
  int f = blk & 63, b = blk >> 6;
  int t = threadIdx.x;
  int row = t >> 2, kg = t & 3;

  const float* Wi = W_ih + f * 12288 + (kg << 4);
  const float* Wh = W_hh + f * 12288 + (kg << 4);
  float wi0[16], wi1[16], wi2[16], wh0[16], wh1[16], wh2[16];
#pragma unroll
  for (int c = 0; c < 4; ++c) {
    *(float4*)&wi0[c*4] = *(const float4*)(Wi + (row << 6)         + (c << 2));
    *(float4*)&wi1[c*4] = *(const float4*)(Wi + ((64 + row) << 6)  + (c << 2));
    *(float4*)&wi2[c*4] = *(const float4*)(Wi + ((128 + row) << 6) + (c << 2));
    *(float4*)&wh0[c*4] = *(const float4*)(Wh + (row << 6)         + (c << 2));
    *(float4*)&wh1[c*4] = *(const float4*)(Wh + ((64 + row) << 6)  + (c << 2));
    *(float4*)&wh2[c*4] = *(const float4*)(Wh + ((128 + row) << 6) + (c << 2));
  }
  float bR  = b_ih[f*192 + row]       + b_hh[f*192 + row];
  float bZ  = b_ih[f*192 + 64 + row]  + b_hh[f*192 + 64 + row];
  float bXN = b_ih[f*192 + 128 + row];
  float bHN = b_hh[f*192 + 128 + row];
  int j2 = t & 31;
  float wd0 = W_dec[(f << 6) + j2], wd1 = W_dec[(f << 6) + 32 + j2];
  float bdec = b_dec[f];
  size_t hidbase = (size_t)b * 262144 + (f << 6);   // hid[b][ts][f][:]
  float hreg = 0.f;

  // ---- stage ALL g rows (own column; coalesced 256B runs) ----
#pragma unroll
  for (int r = 0; r < 4; ++r) {
    int g4 = r * 256 + t;
    int r0 = g4 >> 4, ch = g4 & 15;
    float4 v = *(const float4*)&hid[hidbase + (size_t)r0 * 4096 + (ch << 2)];
    *(float4*)&g_all[r0 * 68 + (ch << 2)] = v;
  }
  if (t < 64) { h_s[0][t] = 0.f; h_s[1][t] = 0.f; }
  __syncthreads();

  // ---- prologue: phase A for group 0 (xw slot [ts] <- group 0) ----
#pragma unroll 4
  for (int ts = 0; ts < 16; ++ts) {
    float gv[16];
#pragma unroll
    for (int c = 0; c < 4; ++c)
      *(float4*)&gv[c*4] = *(const float4*)&g_all[ts * 68 + (kg << 4) + (c << 2)];
    float p0 = 0.f, p1 = 0.f, p2 = 0.f;
#pragma unroll
    for (int k = 0; k < 16; ++k) {
      p0 = fmaf(gv[k], wi0[k], p0);
      p1 = fmaf(gv[k], wi1[k], p1);
      p2 = fmaf(gv[k], wi2[k], p2);
    }
    p0 = qsum(p0); p1 = qsum(p1); p2 = qsum(p2);
    if (kg == 0) {                 // quad-private slot: no barrier needed
      float4 o; o.x = p0; o.y = p1; o.z = p2; o.w = 0.f;
      xw4[(ts << 6) + row] = o;
    }
  }

#pragma unroll 1
  for (int G = 0; G < 4; ++G) {
    // ---- 16 serial steps; lookahead xW for (G+1, ts=st) pipelined in ----
#pragma unroll 2
    for (int st = 0; st < 16; ++st) {
      const int cur = st & 1;
      float4 xg = xw4[(st << 6) + row];            // consume (group G)
      float pr = 0.f, pz = 0.f, pn = 0.f;
#pragma unroll
      for (int c = 0; c < 4; ++c) {
        float4 hv = *(const float4*)&h_s[cur][(kg << 4) + (c << 2)];
        pr = fmaf(hv.x, wh0[c*4+0], pr); pr = fmaf(hv.y, wh0[c*4+1], pr);
        pr = fmaf(hv.z, wh0[c*4+2], pr); pr = fmaf(hv.w, wh0[c*4+3], pr);
        pz = fmaf(hv.x, wh1[c*4+0], pz); pz = fmaf(hv.y, wh1[c*4+1], pz);
        pz = fmaf(hv.z, wh1[c*4+2], pz); pz = fmaf(hv.w, wh1[c*4+3], pz);
        pn = fmaf(hv.x, wh2[c*4+0], pn); pn = fmaf(hv.y, wh2[c*4+1], pn);
        pn = fmaf(hv.z, wh2[c*4+2], pn); pn = fmaf(hv.w, wh2[c*4+3], pn);
      }
      pr = qsum(pr); pz = qsum(pz); pn = qsum(pn);
      float rr = __builtin_amdgcn_rcpf(1.f + __expf(-(pr + xg.x + bR)));
      float zz = __builtin_amdgcn_rcpf(1.f + __expf(-(pz + xg.y + bZ)));
      float pre = fmaf(rr, pn + bHN, xg.z + bXN);
      float nn = 1.f - 2.f * __builtin_amdgcn_rcpf(1.f + __expf(2.f * pre));
      float hnew = fmaf(zz, hreg - nn, nn);
      hreg = hnew;

      if (G < 3) {                                 // produce (group G+1, ts=st)
        int ts2 = ((G + 1) << 4) + st;
        float gv[16];
#pragma unroll
        for (int c = 0; c < 4; ++c)
          *(float4*)&gv[c*4] = *(const float4*)&g_all[ts2 * 68 + (kg << 4) + (c << 2)];
        float q0 = 0.f, q1 = 0.f, q2 = 0.f;
#pragma unroll
        for (int k = 0; k < 16; ++k) {
          q0 = fmaf(gv[k], wi0[k], q0);
          q1 = fmaf(gv[k], wi1[k], q1);
          q2 = fmaf(gv[k], wi2[k], q2);
        }
        q0 = qsum(q0); q1 = qsum(q1); q2 = qsum(q2);
        if (kg == 0) {               // same quad as reader: ordered in-wave
          float4 o; o.x = q0; o.y = q1; o.z = q2; o.w = 0.f;
          xw4[(st << 6) + row] = o;
        }
      }

      if (kg == 0) h_s[cur ^ 1][row] = hnew;
      if (kg == 1) hbuf[(st >> 3) & 1][st & 7][row] = hnew;
      __syncthreads();
      if ((st & 7) == 7) {                  // flush 8 h-rows + fused decode
        const int gsel = (st >> 3) & 1;
        int ts0 = (G << 4) + st - 7;
        if (t < 128) {
          int i = t >> 4, j = t & 15;
          float4 hv4 = *(const float4*)&hbuf[gsel][i][j << 2];
          *(float4*)&hid[hidbase + (size_t)(ts0 + i) * 4096 + (j << 2)] = hv4;
        }
        int i2 = t >> 5;
        float part = hbuf[gsel][i2][j2] * wd0 + hbuf[gsel][i2][j2 + 32] * wd1;
        part += __shfl_xor(part, 1);  part += __shfl_xor(part, 2);
        part += __shfl_xor(part, 4);  part += __shfl_xor(part, 8);
        part += __shfl_xor(part, 16);
        if (j2 == 0) ans[((b << 6) + ts0 + i2) * 64 + f] = part + bdec;
      }
    }
  }
}

extern "C" void kernel_launch(void* const* d_in, const int* in_sizes, int n_in,
                              void* d_out, int out_size, void* d_ws, size_t ws_size,
                              hipStream_t stream) {
  const float* hist   = (const float*)d_in[0];
  const int* src      = (const int*)d_in[1];
  const int* dst      = (const int*)d_in[2];
  const float* W_enc  = (const float*)d_in[3];
  const float* b_enc  = (const float*)d_in[4];
  const float* W_gat  = (const float*)d_in[5];
  const float* attn_l = (const float*)d_in[6];
  const float* attn_r = (const float*)d_in[7];
  const float* b_gat  = (const float*)d_in[8];
  const float* W_ih   = (const float*)d_in[9];
  const float* W_hh   = (const float*)d_in[10];
  const float* b_ih   = (const float*)d_in[11];
  const float* b_hh   = (const float*)d_in[12];
  const float* W_dec  = (const float*)d_in[13];
  const float* b_dec  = (const float*)d_in[14];
  int E = in_sizes[1];

  float* ans = (float*)d_out;
  float* hid = (float*)d_out + Bb * Tt * Ff;   // [B,T,F,H]; holds g then h

  int* off   = (int*)d_ws;                     // 65 used (reserve 256)
  int* csr   = off + 256;                      // E used (reserve 2048)
  float* A   = (float*)(csr + 2048);           // 4096
  float* Bc  = A + 4096;                       // 4096 (b_gat folded)
  float* aA  = Bc + 4096;                      // 256
  float* aB  = aA + 256;
  float* rA  = aB + 256;
  float* rB  = rA + 256;

  hipLaunchKernelGGL(kprep, dim3(2), dim3(256), 0, stream,
                     src, dst, E, W_enc, b_enc, W_gat, attn_l, attn_r, b_gat,
                     off, csr, A, Bc, aA, aB, rA, rB);
  hipLaunchKernelGGL(k_gat, dim3(Bb * Tt), dim3(256), 0, stream,
                     hist, A, Bc, aA, aB, rA, rB, off, csr, E, hid);
  hipLaunchKernelGGL(k_gru, dim3(Ff * Bb), dim3(256), 0, stream,
                     W_ih, W_hh, b_ih, b_hh, W_dec, b_dec, hid, ans);
}

// Round 13
// 177.095 us; speedup vs baseline: 1.3617x; 1.3617x over previous
//
#include <hip/hip_runtime.h>
#include <hip/hip_bf16.h>
#include <math.h>

#define Bb 16
#define Tt 64
#define Ff 64
#define MAXE 2048

// ---------------- kprep: block 0 = CSR build; block 1 = weight tables -------
__global__ __launch_bounds__(256) void kprep(
    const int* __restrict__ src, const int* __restrict__ dst, int E,
    const float* __restrict__ W_enc, const float* __restrict__ b_enc,
    const float* __restrict__ W_gat, const float* __restrict__ attn_l,
    const float* __restrict__ attn_r, const float* __restrict__ b_gat,
    int* __restrict__ off, int* __restrict__ csr,
    float* __restrict__ A, float* __restrict__ Bc,
    float* __restrict__ aA, float* __restrict__ aB,
    float* __restrict__ rA, float* __restrict__ rB) {
  __shared__ int s_src[MAXE], s_dst[MAXE];
  __shared__ int cnt[Ff], base[Ff];
  __shared__ __align__(16) float We[64][64], Be[64][64], Wg[64][64];
  __shared__ __align__(16) float As[64][64], Bs[64][64];
  __shared__ float al_s[64], ar_s[64], bg_s[64];
  int t = threadIdx.x;

  if (blockIdx.x == 0) {                       // ---- CSR by dst ----
    for (int e = t; e < E; e += 256) { s_src[e] = src[e]; s_dst[e] = dst[e]; }
    if (t < Ff) cnt[t] = 0;
    __syncthreads();
    for (int e = t; e < E; e += 256) atomicAdd(&cnt[s_dst[e]], 1);
    __syncthreads();
    if (t == 0) {
      int s = 0;
      for (int i = 0; i < Ff; ++i) { base[i] = s; off[i] = s; s += cnt[i]; }
      off[Ff] = s;
    }
    __syncthreads();
    if (t < Ff) {
      int pos = base[t];
      for (int e = 0; e < E; ++e)
        if (s_dst[e] == t) csr[pos++] = s_src[e];
    }
    return;
  }

  // ---- tables: A = We@Wg, Bc = Be@Wg (+b_gat), attn scalar tables ----
  for (int i = t; i < 1024; i += 256) {
    ((float4*)We)[i] = ((const float4*)W_enc)[i];
    ((float4*)Be)[i] = ((const float4*)b_enc)[i];
    ((float4*)Wg)[i] = ((const float4*)W_gat)[i];
  }
  if (t < 64) { al_s[t] = attn_l[t]; ar_s[t] = attn_r[t]; bg_s[t] = b_gat[t]; }
  __syncthreads();
  int n = t >> 2, q = t & 3;
  float accA[16], accB[16];
#pragma unroll
  for (int j = 0; j < 16; ++j) { accA[j] = 0.f; accB[j] = 0.f; }
  for (int k = 0; k < 64; ++k) {
    float we = We[n][k], be = Be[n][k];
#pragma unroll
    for (int c = 0; c < 4; ++c) {
      float4 wg = *(const float4*)&Wg[k][q * 16 + c * 4];
      accA[c*4+0] = fmaf(we, wg.x, accA[c*4+0]); accB[c*4+0] = fmaf(be, wg.x, accB[c*4+0]);
      accA[c*4+1] = fmaf(we, wg.y, accA[c*4+1]); accB[c*4+1] = fmaf(be, wg.y, accB[c*4+1]);
      accA[c*4+2] = fmaf(we, wg.z, accA[c*4+2]); accB[c*4+2] = fmaf(be, wg.z, accB[c*4+2]);
      accA[c*4+3] = fmaf(we, wg.w, accA[c*4+3]); accB[c*4+3] = fmaf(be, wg.w, accB[c*4+3]);
    }
  }
#pragma unroll
  for (int c = 0; c < 4; ++c) {
    float4 va, vb, vbg;
    va.x = accA[c*4+0]; va.y = accA[c*4+1]; va.z = accA[c*4+2]; va.w = accA[c*4+3];
    vb.x = accB[c*4+0]; vb.y = accB[c*4+1]; vb.z = accB[c*4+2]; vb.w = accB[c*4+3];
    vbg.x = vb.x + bg_s[q*16+c*4+0]; vbg.y = vb.y + bg_s[q*16+c*4+1];
    vbg.z = vb.z + bg_s[q*16+c*4+2]; vbg.w = vb.w + bg_s[q*16+c*4+3];
    *(float4*)&As[n][q*16 + c*4] = va;
    *(float4*)&Bs[n][q*16 + c*4] = vb;       // unfolded (attn tables)
    *(float4*)&A[n*64 + q*16 + c*4] = va;
    *(float4*)&Bc[n*64 + q*16 + c*4] = vbg;  // folded (+b_gat; sum(alpha)=1 => exact)
  }
  __syncthreads();
  float sa = 0.f, sb = 0.f, sra = 0.f, srb = 0.f;
#pragma unroll
  for (int j = 0; j < 16; ++j) {
    float alv = al_s[q*16 + j], arv = ar_s[q*16 + j];
    float av = As[n][q*16 + j], bv = Bs[n][q*16 + j];
    sa  = fmaf(av, alv, sa);  sb  = fmaf(bv, alv, sb);
    sra = fmaf(av, arv, sra); srb = fmaf(bv, arv, srb);
  }
  aA[t] = sa; aB[t] = sb; rA[t] = sra; rB[t] = srb;
}

// ---------------- k_gat: per (b,t); feat staged in LDS once ----------------
__global__ __launch_bounds__(256) void k_gat(
    const float* __restrict__ hist, const float* __restrict__ Ag,
    const float* __restrict__ Bg, const float* __restrict__ aAg,
    const float* __restrict__ aBg, const float* __restrict__ rAg,
    const float* __restrict__ rBg, const int* __restrict__ off,
    const int* __restrict__ csr, int E, float* __restrict__ g_out) {
  __shared__ __align__(16) float feat[64 * 68];   // feat' = x*A + Bc (padded rows)
  __shared__ float x_s[64];
  __shared__ float el_s[64][4], er_s[64][4];
  __shared__ int csr_s[1152];
  __shared__ int off_s[Ff + 1];
  int bt = blockIdx.x, t = threadIdx.x;
  if (t < 64) x_s[t] = hist[bt * 64 + t];
  if (t < Ff + 1) off_s[t] = off[t];
  for (int e = t; e < E; e += 256) csr_s[e] = csr[e];
  __syncthreads();

  // ---- stage feat: thread (s, q) -> feat[s][q*16..+15]; coalesced A/Bc ----
  int s0 = t >> 2, q = t & 3;
  {
    float xs = x_s[s0];
    const float4* Ar = (const float4*)(Ag + (s0 << 6) + (q << 4));
    const float4* Br = (const float4*)(Bg + (s0 << 6) + (q << 4));
#pragma unroll
    for (int c = 0; c < 4; ++c) {
      float4 a4 = Ar[c], b4 = Br[c];
      float4 o;
      o.x = fmaf(xs, a4.x, b4.x); o.y = fmaf(xs, a4.y, b4.y);
      o.z = fmaf(xs, a4.z, b4.z); o.w = fmaf(xs, a4.w, b4.w);
      *(float4*)&feat[s0 * 68 + (q << 4) + (c << 2)] = o;
    }
    el_s[s0][q] = fmaf(xs, aAg[t], aBg[t]);
    er_s[s0][q] = fmaf(xs, rAg[t], rBg[t]);
  }
  __syncthreads();

  // ---- edge phase: thread (d, hd); feat from LDS ----
  int d = s0, hd = q;
  int o0 = off_s[d], o1 = off_s[d + 1];
  float erd = er_s[d][hd];
  float den = 0.f;
  float acc[16];
#pragma unroll
  for (int j = 0; j < 16; ++j) acc[j] = 0.f;
  for (int e = o0; e < o1; ++e) {
    int s = csr_s[e];
    float ee = el_s[s][hd] + erd;
    ee = fmaxf(ee, 0.2f * ee);
    float p = __expf(ee);               // no max-shift: |e| bounded, exact alpha
    den += p;
    const float* fr = &feat[s * 68 + (hd << 4)];
#pragma unroll
    for (int c = 0; c < 4; ++c) {
      float4 fv = *(const float4*)&fr[c << 2];
      acc[c*4+0] = fmaf(p, fv.x, acc[c*4+0]);
      acc[c*4+1] = fmaf(p, fv.y, acc[c*4+1]);
      acc[c*4+2] = fmaf(p, fv.z, acc[c*4+2]);
      acc[c*4+3] = fmaf(p, fv.w, acc[c*4+3]);
    }
  }
  float inv = __builtin_amdgcn_rcpf(den);
  float* gp = g_out + (size_t)bt * 4096 + (d << 6) + (hd << 4);
#pragma unroll
  for (int c = 0; c < 4; ++c) {
    float4 o;
    o.x = acc[c*4+0] * inv; o.y = acc[c*4+1] * inv;
    o.z = acc[c*4+2] * inv; o.w = acc[c*4+3] * inv;
    *(float4*)&gp[c << 2] = o;
  }
}

// ---------------- k_gru: per (f,b) chain; g from own hid column, in place ---
__device__ __forceinline__ float qsum(float v) {
  v += __int_as_float(__builtin_amdgcn_mov_dpp(__float_as_int(v), 0xB1, 0xF, 0xF, true));
  v += __int_as_float(__builtin_amdgcn_mov_dpp(__float_as_int(v), 0x4E, 0xF, 0xF, true));
  return v;
}

__global__ __launch_bounds__(256, 4) void k_gru(
    const float* __restrict__ W_ih, const float* __restrict__ W_hh,
    const float* __restrict__ b_ih, const float* __restrict__ b_hh,
    const float* __restrict__ W_dec, const float* __restrict__ b_dec,
    float* __restrict__ hid, float* __restrict__ ans) {
  __shared__ __align__(16) float g_g[16 * 68];    // one group's g, padded rows
  __shared__ __align__(16) float xw_s[3 * 16 * 64];
  __shared__ __align__(16) float h_s[2][64];
  __shared__ __align__(16) float hbuf[2][8][64];
  int blk = blockIdx.x;
  int f = blk & 63, b = blk >> 6;
  int t = threadIdx.x;
  int row = t >> 2, kg = t & 3;

  const float* Wi = W_ih + f * 12288 + (kg << 4);
  const float* Wh = W_hh + f * 12288 + (kg << 4);
  float wi0[16], wi1[16], wi2[16], wh0[16], wh1[16], wh2[16];
#pragma unroll
  for (int c = 0; c < 4; ++c) {
    *(float4*)&wi0[c*4] = *(const float4*)(Wi + (row << 6)         + (c << 2));
    *(float4*)&wi1[c*4] = *(const float4*)(Wi + ((64 + row) << 6)  + (c << 2));
    *(float4*)&wi2[c*4] = *(const float4*)(Wi + ((128 + row) << 6) + (c << 2));
    *(float4*)&wh0[c*4] = *(const float4*)(Wh + (row << 6)         + (c << 2));
    *(float4*)&wh1[c*4] = *(const float4*)(Wh + ((64 + row) << 6)  + (c << 2));
    *(float4*)&wh2[c*4] = *(const float4*)(Wh + ((128 + row) << 6) + (c << 2));
  }
  float bR  = b_ih[f*192 + row]       + b_hh[f*192 + row];
  float bZ  = b_ih[f*192 + 64 + row]  + b_hh[f*192 + 64 + row];
  float bXN = b_ih[f*192 + 128 + row];
  float bHN = b_hh[f*192 + 128 + row];
  int j2 = t & 31;
  float wd0 = W_dec[(f << 6) + j2], wd1 = W_dec[(f << 6) + 32 + j2];
  float bdec = b_dec[f];
  size_t hidbase = (size_t)b * 262144 + (f << 6);   // hid[b][ts][f][:]
  float hreg = 0.f;
  if (t < 64) { h_s[0][t] = 0.f; h_s[1][t] = 0.f; }
  __syncthreads();

#pragma unroll 1
  for (int G = 0; G < 4; ++G) {
    // ---- stage this group's g (own column; rows not yet overwritten) ----
    {
      int i = t >> 4, ch = t & 15;
      float4 v = *(const float4*)&hid[hidbase + (size_t)((G << 4) + i) * 4096 + (ch << 2)];
      *(float4*)&g_g[i * 68 + (ch << 2)] = v;
    }
    __syncthreads();

    // ---- phase A: g-row read once per ts; 3 gate partials; xw -> LDS ----
#pragma unroll
    for (int ts = 0; ts < 16; ++ts) {
      float gv[16];
#pragma unroll
      for (int c = 0; c < 4; ++c)
        *(float4*)&gv[c*4] = *(const float4*)&g_g[ts * 68 + (kg << 4) + (c << 2)];
      float p0 = 0.f, p1 = 0.f, p2 = 0.f;
#pragma unroll
      for (int k = 0; k < 16; ++k) {
        p0 = fmaf(gv[k], wi0[k], p0);
        p1 = fmaf(gv[k], wi1[k], p1);
        p2 = fmaf(gv[k], wi2[k], p2);
      }
      p0 = qsum(p0); p1 = qsum(p1); p2 = qsum(p2);
      if (kg == 0) {                   // wave-private rows: no barrier needed
        xw_s[(ts << 6) + row]        = p0;
        xw_s[1024 + (ts << 6) + row] = p1;
        xw_s[2048 + (ts << 6) + row] = p2;
      }
    }

    // ---- 16 serial GRU steps (fully unrolled, static indices) ----
#pragma unroll
    for (int st = 0; st < 16; ++st) {
      const int cur = st & 1;
      float xr = xw_s[(st << 6) + row];
      float xz = xw_s[1024 + (st << 6) + row];
      float xn = xw_s[2048 + (st << 6) + row];
      float pr = 0.f, pz = 0.f, pn = 0.f;
#pragma unroll
      for (int c = 0; c < 4; ++c) {
        float4 hv = *(const float4*)&h_s[cur][(kg << 4) + (c << 2)];
        pr = fmaf(hv.x, wh0[c*4+0], pr); pr = fmaf(hv.y, wh0[c*4+1], pr);
        pr = fmaf(hv.z, wh0[c*4+2], pr); pr = fmaf(hv.w, wh0[c*4+3], pr);
        pz = fmaf(hv.x, wh1[c*4+0], pz); pz = fmaf(hv.y, wh1[c*4+1], pz);
        pz = fmaf(hv.z, wh1[c*4+2], pz); pz = fmaf(hv.w, wh1[c*4+3], pz);
        pn = fmaf(hv.x, wh2[c*4+0], pn); pn = fmaf(hv.y, wh2[c*4+1], pn);
        pn = fmaf(hv.z, wh2[c*4+2], pn); pn = fmaf(hv.w, wh2[c*4+3], pn);
      }
      pr = qsum(pr); pz = qsum(pz); pn = qsum(pn);
      float rr = __builtin_amdgcn_rcpf(1.f + __expf(-(pr + xr + bR)));
      float zz = __builtin_amdgcn_rcpf(1.f + __expf(-(pz + xz + bZ)));
      float pre = fmaf(rr, pn + bHN, xn + bXN);
      float nn = 1.f - 2.f * __builtin_amdgcn_rcpf(1.f + __expf(2.f * pre));
      float hnew = fmaf(zz, hreg - nn, nn);
      hreg = hnew;
      if (kg == 0) h_s[cur ^ 1][row] = hnew;
      if (kg == 1) hbuf[(st >> 3) & 1][st & 7][row] = hnew;
      __syncthreads();
      if ((st & 7) == 7) {                  // flush 8 h-rows + fused decode
        const int gsel = (st >> 3) & 1;
        int ts0 = (G << 4) + st - 7;
        if (t < 128) {
          int i = t >> 4, j = t & 15;
          float4 hv4 = *(const float4*)&hbuf[gsel][i][j << 2];
          *(float4*)&hid[hidbase + (size_t)(ts0 + i) * 4096 + (j << 2)] = hv4;
        }
        int i2 = t >> 5;
        float part = hbuf[gsel][i2][j2] * wd0 + hbuf[gsel][i2][j2 + 32] * wd1;
        part += __shfl_xor(part, 1);  part += __shfl_xor(part, 2);
        part += __shfl_xor(part, 4);  part += __shfl_xor(part, 8);
        part += __shfl_xor(part, 16);
        if (j2 == 0) ans[((b << 6) + ts0 + i2) * 64 + f] = part + bdec;
      }
    }
  }
}

extern "C" void kernel_launch(void* const* d_in, const int* in_sizes, int n_in,
                              void* d_out, int out_size, void* d_ws, size_t ws_size,
                              hipStream_t stream) {
  const float* hist   = (const float*)d_in[0];
  const int* src      = (const int*)d_in[1];
  const int* dst      = (const int*)d_in[2];
  const float* W_enc  = (const float*)d_in[3];
  const float* b_enc  = (const float*)d_in[4];
  const float* W_gat  = (const float*)d_in[5];
  const float* attn_l = (const float*)d_in[6];
  const float* attn_r = (const float*)d_in[7];
  const float* b_gat  = (const float*)d_in[8];
  const float* W_ih   = (const float*)d_in[9];
  const float* W_hh   = (const float*)d_in[10];
  const float* b_ih   = (const float*)d_in[11];
  const float* b_hh   = (const float*)d_in[12];
  const float* W_dec  = (const float*)d_in[13];
  const float* b_dec  = (const float*)d_in[14];
  int E = in_sizes[1];

  float* ans = (float*)d_out;
  float* hid = (float*)d_out + Bb * Tt * Ff;   // [B,T,F,H]; holds g then h

  int* off   = (int*)d_ws;                     // 65 used (reserve 256)
  int* csr   = off + 256;                      // E used (reserve 2048)
  float* A   = (float*)(csr + 2048);           // 4096
  float* Bc  = A + 4096;                       // 4096 (b_gat folded)
  float* aA  = Bc + 4096;                      // 256
  float* aB  = aA + 256;
  float* rA  = aB + 256;
  float* rB  = rA + 256;

  hipLaunchKernelGGL(kprep, dim3(2), dim3(256), 0, stream,
                     src, dst, E, W_enc, b_enc, W_gat, attn_l, attn_r, b_gat,
                     off, csr, A, Bc, aA, aB, rA, rB);
  hipLaunchKernelGGL(k_gat, dim3(Bb * Tt), dim3(256), 0, stream,
                     hist, A, Bc, aA, aB, rA, rB, off, csr, E, hid);
  hipLaunchKernelGGL(k_gru, dim3(Ff * Bb), dim3(256), 0, stream,
                     W_ih, W_hh, b_ih, b_hh, W_dec, b_dec, hid, ans);
}

// Round 14
// 145.166 us; speedup vs baseline: 1.6612x; 1.2199x over previous
//
#include <hip/hip_runtime.h>
#include <hip/hip_bf16.h>
#include <math.h>

#define Bb 16
#define Tt 64
#define Ff 64
#define MAXE 2048

// ---------------- kprep: block 0 = CSR build; block 1 = weight tables -------
__global__ __launch_bounds__(256) void kprep(
    const int* __restrict__ src, const int* __restrict__ dst, int E,
    const float* __restrict__ W_enc, const float* __restrict__ b_enc,
    const float* __restrict__ W_gat, const float* __restrict__ attn_l,
    const float* __restrict__ attn_r, const float* __restrict__ b_gat,
    int* __restrict__ off, int* __restrict__ csr,
    float* __restrict__ A, float* __restrict__ Bc,
    float* __restrict__ aA, float* __restrict__ aB,
    float* __restrict__ rA, float* __restrict__ rB) {
  __shared__ int s_src[MAXE], s_dst[MAXE];
  __shared__ int cnt[Ff], base[Ff];
  __shared__ __align__(16) float We[64][64], Be[64][64], Wg[64][64];
  __shared__ __align__(16) float As[64][64], Bs[64][64];
  __shared__ float al_s[64], ar_s[64], bg_s[64];
  int t = threadIdx.x;

  if (blockIdx.x == 0) {                       // ---- CSR by dst ----
    for (int e = t; e < E; e += 256) { s_src[e] = src[e]; s_dst[e] = dst[e]; }
    if (t < Ff) cnt[t] = 0;
    __syncthreads();
    for (int e = t; e < E; e += 256) atomicAdd(&cnt[s_dst[e]], 1);
    __syncthreads();
    if (t == 0) {
      int s = 0;
      for (int i = 0; i < Ff; ++i) { base[i] = s; off[i] = s; s += cnt[i]; }
      off[Ff] = s;
    }
    __syncthreads();
    // wave-cooperative order-preserving scatter: chunk of 64 edges -> regs,
    // then 64 readlane broadcast steps (register-only, no LDS latency chain)
    if (t < 64) {
      int pos = base[t];
      for (int be = 0; be < E; be += 64) {
        int e = be + t;
        int d  = (e < E) ? s_dst[e] : -1;
        int sv = (e < E) ? s_src[e] : 0;
#pragma unroll 8
        for (int j = 0; j < 64; ++j) {
          int dj = __builtin_amdgcn_readlane(d, j);
          int sj = __builtin_amdgcn_readlane(sv, j);
          if (t == dj) csr[pos++] = sj;
        }
      }
    }
    return;
  }

  // ---- tables: A = We@Wg, Bc = Be@Wg (+b_gat), attn scalar tables ----
  for (int i = t; i < 1024; i += 256) {
    ((float4*)We)[i] = ((const float4*)W_enc)[i];
    ((float4*)Be)[i] = ((const float4*)b_enc)[i];
    ((float4*)Wg)[i] = ((const float4*)W_gat)[i];
  }
  if (t < 64) { al_s[t] = attn_l[t]; ar_s[t] = attn_r[t]; bg_s[t] = b_gat[t]; }
  __syncthreads();
  int n = t >> 2, q = t & 3;
  float accA[16], accB[16];
#pragma unroll
  for (int j = 0; j < 16; ++j) { accA[j] = 0.f; accB[j] = 0.f; }
  for (int k = 0; k < 64; ++k) {
    float we = We[n][k], be = Be[n][k];
#pragma unroll
    for (int c = 0; c < 4; ++c) {
      float4 wg = *(const float4*)&Wg[k][q * 16 + c * 4];
      accA[c*4+0] = fmaf(we, wg.x, accA[c*4+0]); accB[c*4+0] = fmaf(be, wg.x, accB[c*4+0]);
      accA[c*4+1] = fmaf(we, wg.y, accA[c*4+1]); accB[c*4+1] = fmaf(be, wg.y, accB[c*4+1]);
      accA[c*4+2] = fmaf(we, wg.z, accA[c*4+2]); accB[c*4+2] = fmaf(be, wg.z, accB[c*4+2]);
      accA[c*4+3] = fmaf(we, wg.w, accA[c*4+3]); accB[c*4+3] = fmaf(be, wg.w, accB[c*4+3]);
    }
  }
#pragma unroll
  for (int c = 0; c < 4; ++c) {
    float4 va, vb, vbg;
    va.x = accA[c*4+0]; va.y = accA[c*4+1]; va.z = accA[c*4+2]; va.w = accA[c*4+3];
    vb.x = accB[c*4+0]; vb.y = accB[c*4+1]; vb.z = accB[c*4+2]; vb.w = accB[c*4+3];
    vbg.x = vb.x + bg_s[q*16+c*4+0]; vbg.y = vb.y + bg_s[q*16+c*4+1];
    vbg.z = vb.z + bg_s[q*16+c*4+2]; vbg.w = vb.w + bg_s[q*16+c*4+3];
    *(float4*)&As[n][q*16 + c*4] = va;
    *(float4*)&Bs[n][q*16 + c*4] = vb;       // unfolded (attn tables)
    *(float4*)&A[n*64 + q*16 + c*4] = va;
    *(float4*)&Bc[n*64 + q*16 + c*4] = vbg;  // folded (+b_gat; sum(alpha)=1 => exact)
  }
  __syncthreads();
  float sa = 0.f, sb = 0.f, sra = 0.f, srb = 0.f;
#pragma unroll
  for (int j = 0; j < 16; ++j) {
    float alv = al_s[q*16 + j], arv = ar_s[q*16 + j];
    float av = As[n][q*16 + j], bv = Bs[n][q*16 + j];
    sa  = fmaf(av, alv, sa);  sb  = fmaf(bv, alv, sb);
    sra = fmaf(av, arv, sra); srb = fmaf(bv, arv, srb);
  }
  aA[t] = sa; aB[t] = sb; rA[t] = sra; rB[t] = srb;
}

// ---------------- k_gat: per (b,t); feat staged in LDS once ----------------
__global__ __launch_bounds__(256) void k_gat(
    const float* __restrict__ hist, const float* __restrict__ Ag,
    const float* __restrict__ Bg, const float* __restrict__ aAg,
    const float* __restrict__ aBg, const float* __restrict__ rAg,
    const float* __restrict__ rBg, const int* __restrict__ off,
    const int* __restrict__ csr, int E, float* __restrict__ g_out) {
  __shared__ __align__(16) float feat[64 * 68];   // feat' = x*A + Bc (padded rows)
  __shared__ float x_s[64];
  __shared__ float el_s[64][4], er_s[64][4];
  __shared__ int csr_s[1152];
  __shared__ int off_s[Ff + 1];
  int bt = blockIdx.x, t = threadIdx.x;
  if (t < 64) x_s[t] = hist[bt * 64 + t];
  if (t < Ff + 1) off_s[t] = off[t];
  for (int e = t; e < E; e += 256) csr_s[e] = csr[e];
  __syncthreads();

  // ---- stage feat: thread (s, q) -> feat[s][q*16..+15]; coalesced A/Bc ----
  int s0 = t >> 2, q = t & 3;
  {
    float xs = x_s[s0];
    const float4* Ar = (const float4*)(Ag + (s0 << 6) + (q << 4));
    const float4* Br = (const float4*)(Bg + (s0 << 6) + (q << 4));
#pragma unroll
    for (int c = 0; c < 4; ++c) {
      float4 a4 = Ar[c], b4 = Br[c];
      float4 o;
      o.x = fmaf(xs, a4.x, b4.x); o.y = fmaf(xs, a4.y, b4.y);
      o.z = fmaf(xs, a4.z, b4.z); o.w = fmaf(xs, a4.w, b4.w);
      *(float4*)&feat[s0 * 68 + (q << 4) + (c << 2)] = o;
    }
    el_s[s0][q] = fmaf(xs, aAg[t], aBg[t]);
    er_s[s0][q] = fmaf(xs, rAg[t], rBg[t]);
  }
  __syncthreads();

  // ---- edge phase: thread (d, hd); feat from LDS ----
  int d = s0, hd = q;
  int o0 = off_s[d], o1 = off_s[d + 1];
  float erd = er_s[d][hd];
  float den = 0.f;
  float acc[16];
#pragma unroll
  for (int j = 0; j < 16; ++j) acc[j] = 0.f;
  for (int e = o0; e < o1; ++e) {
    int s = csr_s[e];
    float ee = el_s[s][hd] + erd;
    ee = fmaxf(ee, 0.2f * ee);
    float p = __expf(ee);               // no max-shift: |e| bounded, exact alpha
    den += p;
    const float* fr = &feat[s * 68 + (hd << 4)];
#pragma unroll
    for (int c = 0; c < 4; ++c) {
      float4 fv = *(const float4*)&fr[c << 2];
      acc[c*4+0] = fmaf(p, fv.x, acc[c*4+0]);
      acc[c*4+1] = fmaf(p, fv.y, acc[c*4+1]);
      acc[c*4+2] = fmaf(p, fv.z, acc[c*4+2]);
      acc[c*4+3] = fmaf(p, fv.w, acc[c*4+3]);
    }
  }
  float inv = __builtin_amdgcn_rcpf(den);
  float* gp = g_out + (size_t)bt * 4096 + (d << 6) + (hd << 4);
#pragma unroll
  for (int c = 0; c < 4; ++c) {
    float4 o;
    o.x = acc[c*4+0] * inv; o.y = acc[c*4+1] * inv;
    o.z = acc[c*4+2] * inv; o.w = acc[c*4+3] * inv;
    *(float4*)&gp[c << 2] = o;
  }
}

// ---------------- k_gru: per (f,b) chain; g from own hid column, in place ---
__device__ __forceinline__ float qsum(float v) {
  v += __int_as_float(__builtin_amdgcn_mov_dpp(__float_as_int(v), 0xB1, 0xF, 0xF, true));
  v += __int_as_float(__builtin_amdgcn_mov_dpp(__float_as_int(v), 0x4E, 0xF, 0xF, true));
  return v;
}

__global__ __launch_bounds__(256, 4) void k_gru(
    const float* __restrict__ W_ih, const float* __restrict__ W_hh,
    const float* __restrict__ b_ih, const float* __restrict__ b_hh,
    const float* __restrict__ W_dec, const float* __restrict__ b_dec,
    float* __restrict__ hid, float* __restrict__ ans) {
  __shared__ __align__(16) float g_g[16 * 68];    // one group's g, padded rows
  __shared__ __align__(16) float xw_s[3 * 16 * 64];
  __shared__ __align__(16) float h_s[2][64];
  __shared__ __align__(16) float hbuf[2][8][64];
  int blk = blockIdx.x;
  int f = blk & 63, b = blk >> 6;
  int t = threadIdx.x;
  int row = t >> 2, kg = t & 3;

  const float* Wi = W_ih + f * 12288 + (kg << 4);
  const float* Wh = W_hh + f * 12288 + (kg << 4);
  float wi0[16], wi1[16], wi2[16], wh0[16], wh1[16], wh2[16];
#pragma unroll
  for (int c = 0; c < 4; ++c) {
    *(float4*)&wi0[c*4] = *(const float4*)(Wi + (row << 6)         + (c << 2));
    *(float4*)&wi1[c*4] = *(const float4*)(Wi + ((64 + row) << 6)  + (c << 2));
    *(float4*)&wi2[c*4] = *(const float4*)(Wi + ((128 + row) << 6) + (c << 2));
    *(float4*)&wh0[c*4] = *(const float4*)(Wh + (row << 6)         + (c << 2));
    *(float4*)&wh1[c*4] = *(const float4*)(Wh + ((64 + row) << 6)  + (c << 2));
    *(float4*)&wh2[c*4] = *(const float4*)(Wh + ((128 + row) << 6) + (c << 2));
  }
  float bR  = b_ih[f*192 + row]       + b_hh[f*192 + row];
  float bZ  = b_ih[f*192 + 64 + row]  + b_hh[f*192 + 64 + row];
  float bXN = b_ih[f*192 + 128 + row];
  float bHN = b_hh[f*192 + 128 + row];
  int j2 = t & 31;
  float wd0 = W_dec[(f << 6) + j2], wd1 = W_dec[(f << 6) + 32 + j2];
  float bdec = b_dec[f];
  size_t hidbase = (size_t)b * 262144 + (f << 6);   // hid[b][ts][f][:]
  float hreg = 0.f;
  if (t < 64) { h_s[0][t] = 0.f; h_s[1][t] = 0.f; }
  __syncthreads();

#pragma unroll 1
  for (int G = 0; G < 4; ++G) {
    // ---- stage this group's g (own column; rows not yet overwritten) ----
    {
      int i = t >> 4, ch = t & 15;
      float4 v = *(const float4*)&hid[hidbase + (size_t)((G << 4) + i) * 4096 + (ch << 2)];
      *(float4*)&g_g[i * 68 + (ch << 2)] = v;
    }
    __syncthreads();

    // ---- phase A: g-row read once per ts; 3 gate partials; xw -> LDS ----
#pragma unroll
    for (int ts = 0; ts < 16; ++ts) {
      float gv[16];
#pragma unroll
      for (int c = 0; c < 4; ++c)
        *(float4*)&gv[c*4] = *(const float4*)&g_g[ts * 68 + (kg << 4) + (c << 2)];
      float p0 = 0.f, p1 = 0.f, p2 = 0.f;
#pragma unroll
      for (int k = 0; k < 16; ++k) {
        p0 = fmaf(gv[k], wi0[k], p0);
        p1 = fmaf(gv[k], wi1[k], p1);
        p2 = fmaf(gv[k], wi2[k], p2);
      }
      p0 = qsum(p0); p1 = qsum(p1); p2 = qsum(p2);
      if (kg == 0) {                   // wave-private rows: no barrier needed
        xw_s[(ts << 6) + row]        = p0;
        xw_s[1024 + (ts << 6) + row] = p1;
        xw_s[2048 + (ts << 6) + row] = p2;
      }
    }

    // ---- 16 serial GRU steps (fully unrolled, static indices) ----
#pragma unroll
    for (int st = 0; st < 16; ++st) {
      const int cur = st & 1;
      float xr = xw_s[(st << 6) + row];
      float xz = xw_s[1024 + (st << 6) + row];
      float xn = xw_s[2048 + (st << 6) + row];
      float pr = 0.f, pz = 0.f, pn = 0.f;
#pragma unroll
      for (int c = 0; c < 4; ++c) {
        float4 hv = *(const float4*)&h_s[cur][(kg << 4) + (c << 2)];
        pr = fmaf(hv.x, wh0[c*4+0], pr); pr = fmaf(hv.y, wh0[c*4+1], pr);
        pr = fmaf(hv.z, wh0[c*4+2], pr); pr = fmaf(hv.w, wh0[c*4+3], pr);
        pz = fmaf(hv.x, wh1[c*4+0], pz); pz = fmaf(hv.y, wh1[c*4+1], pz);
        pz = fmaf(hv.z, wh1[c*4+2], pz); pz = fmaf(hv.w, wh1[c*4+3], pz);
        pn = fmaf(hv.x, wh2[c*4+0], pn); pn = fmaf(hv.y, wh2[c*4+1], pn);
        pn = fmaf(hv.z, wh2[c*4+2], pn); pn = fmaf(hv.w, wh2[c*4+3], pn);
      }
      pr = qsum(pr); pz = qsum(pz); pn = qsum(pn);
      float rr = __builtin_amdgcn_rcpf(1.f + __expf(-(pr + xr + bR)));
      float zz = __builtin_amdgcn_rcpf(1.f + __expf(-(pz + xz + bZ)));
      float pre = fmaf(rr, pn + bHN, xn + bXN);
      float nn = 1.f - 2.f * __builtin_amdgcn_rcpf(1.f + __expf(2.f * pre));
      float hnew = fmaf(zz, hreg - nn, nn);
      hreg = hnew;
      if (kg == 0) h_s[cur ^ 1][row] = hnew;
      if (kg == 1) hbuf[(st >> 3) & 1][st & 7][row] = hnew;
      __syncthreads();
      if ((st & 7) == 7) {                  // flush 8 h-rows + fused decode
        const int gsel = (st >> 3) & 1;
        int ts0 = (G << 4) + st - 7;
        if (t < 128) {
          int i = t >> 4, j = t & 15;
          float4 hv4 = *(const float4*)&hbuf[gsel][i][j << 2];
          *(float4*)&hid[hidbase + (size_t)(ts0 + i) * 4096 + (j << 2)] = hv4;
        }
        int i2 = t >> 5;
        float part = hbuf[gsel][i2][j2] * wd0 + hbuf[gsel][i2][j2 + 32] * wd1;
        part += __shfl_xor(part, 1);  part += __shfl_xor(part, 2);
        part += __shfl_xor(part, 4);  part += __shfl_xor(part, 8);
        part += __shfl_xor(part, 16);
        if (j2 == 0) ans[((b << 6) + ts0 + i2) * 64 + f] = part + bdec;
      }
    }
  }
}

extern "C" void kernel_launch(void* const* d_in, const int* in_sizes, int n_in,
                              void* d_out, int out_size, void* d_ws, size_t ws_size,
                              hipStream_t stream) {
  const float* hist   = (const float*)d_in[0];
  const int* src      = (const int*)d_in[1];
  const int* dst      = (const int*)d_in[2];
  const float* W_enc  = (const float*)d_in[3];
  const float* b_enc  = (const float*)d_in[4];
  const float* W_gat  = (const float*)d_in[5];
  const float* attn_l = (const float*)d_in[6];
  const float* attn_r = (const float*)d_in[7];
  const float* b_gat  = (const float*)d_in[8];
  const float* W_ih   = (const float*)d_in[9];
  const float* W_hh   = (const float*)d_in[10];
  const float* b_ih   = (const float*)d_in[11];
  const float* b_hh   = (const float*)d_in[12];
  const float* W_dec  = (const float*)d_in[13];
  const float* b_dec  = (const float*)d_in[14];
  int E = in_sizes[1];

  float* ans = (float*)d_out;
  float* hid = (float*)d_out + Bb * Tt * Ff;   // [B,T,F,H]; holds g then h

  int* off   = (int*)d_ws;                     // 65 used (reserve 256)
  int* csr   = off + 256;                      // E used (reserve 2048)
  float* A   = (float*)(csr + 2048);           // 4096
  float* Bc  = A + 4096;                       // 4096 (b_gat folded)
  float* aA  = Bc + 4096;                      // 256
  float* aB  = aA + 256;
  float* rA  = aB + 256;
  float* rB  = rA + 256;

  hipLaunchKernelGGL(kprep, dim3(2), dim3(256), 0, stream,
                     src, dst, E, W_enc, b_enc, W_gat, attn_l, attn_r, b_gat,
                     off, csr, A, Bc, aA, aB, rA, rB);
  hipLaunchKernelGGL(k_gat, dim3(Bb * Tt), dim3(256), 0, stream,
                     hist, A, Bc, aA, aB, rA, rB, off, csr, E, hid);
  hipLaunchKernelGGL(k_gru, dim3(Ff * Bb), dim3(256), 0, stream,
                     W_ih, W_hh, b_ih, b_hh, W_dec, b_dec, hid, ans);
}

// Round 16
// 136.735 us; speedup vs baseline: 1.7637x; 1.0617x over previous
//
#include <hip/hip_runtime.h>
#include <hip/hip_bf16.h>
#include <math.h>

#define Bb 16
#define Tt 64
#define Ff 64
#define MAXE 2048

typedef __fp16 h2f __attribute__((ext_vector_type(2)));
__device__ __forceinline__ h2f pkh(float a, float b) {
  return __builtin_amdgcn_cvt_pkrtz(a, b);
}

// ---------------- kprep: block 0 = CSR build; block 1 = weight tables -------
__global__ __launch_bounds__(256) void kprep(
    const int* __restrict__ src, const int* __restrict__ dst, int E,
    const float* __restrict__ W_enc, const float* __restrict__ b_enc,
    const float* __restrict__ W_gat, const float* __restrict__ attn_l,
    const float* __restrict__ attn_r, const float* __restrict__ b_gat,
    int* __restrict__ off, int* __restrict__ csr,
    float* __restrict__ A, float* __restrict__ Bc,
    float* __restrict__ aA, float* __restrict__ aB,
    float* __restrict__ rA, float* __restrict__ rB) {
  __shared__ int s_src[MAXE], s_dst[MAXE];
  __shared__ int cnt[Ff], base[Ff];
  __shared__ __align__(16) float We[64][64], Be[64][64], Wg[64][64];
  __shared__ __align__(16) float As[64][64], Bs[64][64];
  __shared__ float al_s[64], ar_s[64], bg_s[64];
  int t = threadIdx.x;

  if (blockIdx.x == 0) {                       // ---- CSR by dst ----
    for (int e = t; e < E; e += 256) { s_src[e] = src[e]; s_dst[e] = dst[e]; }
    if (t < Ff) cnt[t] = 0;
    __syncthreads();
    for (int e = t; e < E; e += 256) atomicAdd(&cnt[s_dst[e]], 1);
    __syncthreads();
    if (t == 0) {
      int s = 0;
      for (int i = 0; i < Ff; ++i) { base[i] = s; off[i] = s; s += cnt[i]; }
      off[Ff] = s;
    }
    __syncthreads();
    // wave-cooperative order-preserving scatter: chunk of 64 edges -> regs,
    // then 64 readlane broadcast steps (register-only, no LDS latency chain)
    if (t < 64) {
      int pos = base[t];
      for (int be = 0; be < E; be += 64) {
        int e = be + t;
        int d  = (e < E) ? s_dst[e] : -1;
        int sv = (e < E) ? s_src[e] : 0;
#pragma unroll 8
        for (int j = 0; j < 64; ++j) {
          int dj = __builtin_amdgcn_readlane(d, j);
          int sj = __builtin_amdgcn_readlane(sv, j);
          if (t == dj) csr[pos++] = sj;
        }
      }
    }
    return;
  }

  // ---- tables: A = We@Wg, Bc = Be@Wg (+b_gat), attn scalar tables ----
  for (int i = t; i < 1024; i += 256) {
    ((float4*)We)[i] = ((const float4*)W_enc)[i];
    ((float4*)Be)[i] = ((const float4*)b_enc)[i];
    ((float4*)Wg)[i] = ((const float4*)W_gat)[i];
  }
  if (t < 64) { al_s[t] = attn_l[t]; ar_s[t] = attn_r[t]; bg_s[t] = b_gat[t]; }
  __syncthreads();
  int n = t >> 2, q = t & 3;
  float accA[16], accB[16];
#pragma unroll
  for (int j = 0; j < 16; ++j) { accA[j] = 0.f; accB[j] = 0.f; }
  for (int k = 0; k < 64; ++k) {
    float we = We[n][k], be = Be[n][k];
#pragma unroll
    for (int c = 0; c < 4; ++c) {
      float4 wg = *(const float4*)&Wg[k][q * 16 + c * 4];
      accA[c*4+0] = fmaf(we, wg.x, accA[c*4+0]); accB[c*4+0] = fmaf(be, wg.x, accB[c*4+0]);
      accA[c*4+1] = fmaf(we, wg.y, accA[c*4+1]); accB[c*4+1] = fmaf(be, wg.y, accB[c*4+1]);
      accA[c*4+2] = fmaf(we, wg.z, accA[c*4+2]); accB[c*4+2] = fmaf(be, wg.z, accB[c*4+2]);
      accA[c*4+3] = fmaf(we, wg.w, accA[c*4+3]); accB[c*4+3] = fmaf(be, wg.w, accB[c*4+3]);
    }
  }
#pragma unroll
  for (int c = 0; c < 4; ++c) {
    float4 va, vb, vbg;
    va.x = accA[c*4+0]; va.y = accA[c*4+1]; va.z = accA[c*4+2]; va.w = accA[c*4+3];
    vb.x = accB[c*4+0]; vb.y = accB[c*4+1]; vb.z = accB[c*4+2]; vb.w = accB[c*4+3];
    vbg.x = vb.x + bg_s[q*16+c*4+0]; vbg.y = vb.y + bg_s[q*16+c*4+1];
    vbg.z = vb.z + bg_s[q*16+c*4+2]; vbg.w = vb.w + bg_s[q*16+c*4+3];
    *(float4*)&As[n][q*16 + c*4] = va;
    *(float4*)&Bs[n][q*16 + c*4] = vb;       // unfolded (attn tables)
    *(float4*)&A[n*64 + q*16 + c*4] = va;
    *(float4*)&Bc[n*64 + q*16 + c*4] = vbg;  // folded (+b_gat; sum(alpha)=1 => exact)
  }
  __syncthreads();
  float sa = 0.f, sb = 0.f, sra = 0.f, srb = 0.f;
#pragma unroll
  for (int j = 0; j < 16; ++j) {
    float alv = al_s[q*16 + j], arv = ar_s[q*16 + j];
    float av = As[n][q*16 + j], bv = Bs[n][q*16 + j];
    sa  = fmaf(av, alv, sa);  sb  = fmaf(bv, alv, sb);
    sra = fmaf(av, arv, sra); srb = fmaf(bv, arv, srb);
  }
  aA[t] = sa; aB[t] = sb; rA[t] = sra; rB[t] = srb;
}

// ---------------- k_gat: per (b,t); feat staged in LDS once ----------------
__global__ __launch_bounds__(256) void k_gat(
    const float* __restrict__ hist, const float* __restrict__ Ag,
    const float* __restrict__ Bg, const float* __restrict__ aAg,
    const float* __restrict__ aBg, const float* __restrict__ rAg,
    const float* __restrict__ rBg, const int* __restrict__ off,
    const int* __restrict__ csr, int E, float* __restrict__ g_out) {
  __shared__ __align__(16) float feat[64 * 68];   // feat' = x*A + Bc (padded rows)
  __shared__ float x_s[64];
  __shared__ float el_s[64][4], er_s[64][4];
  __shared__ int csr_s[1152];
  __shared__ int off_s[Ff + 1];
  int bt = blockIdx.x, t = threadIdx.x;
  if (t < 64) x_s[t] = hist[bt * 64 + t];
  if (t < Ff + 1) off_s[t] = off[t];
  for (int e = t; e < E; e += 256) csr_s[e] = csr[e];
  __syncthreads();

  // ---- stage feat: thread (s, q) -> feat[s][q*16..+15]; coalesced A/Bc ----
  int s0 = t >> 2, q = t & 3;
  {
    float xs = x_s[s0];
    const float4* Ar = (const float4*)(Ag + (s0 << 6) + (q << 4));
    const float4* Br = (const float4*)(Bg + (s0 << 6) + (q << 4));
#pragma unroll
    for (int c = 0; c < 4; ++c) {
      float4 a4 = Ar[c], b4 = Br[c];
      float4 o;
      o.x = fmaf(xs, a4.x, b4.x); o.y = fmaf(xs, a4.y, b4.y);
      o.z = fmaf(xs, a4.z, b4.z); o.w = fmaf(xs, a4.w, b4.w);
      *(float4*)&feat[s0 * 68 + (q << 4) + (c << 2)] = o;
    }
    el_s[s0][q] = fmaf(xs, aAg[t], aBg[t]);
    er_s[s0][q] = fmaf(xs, rAg[t], rBg[t]);
  }
  __syncthreads();

  // ---- edge phase: thread (d, hd); feat from LDS ----
  int d = s0, hd = q;
  int o0 = off_s[d], o1 = off_s[d + 1];
  float erd = er_s[d][hd];
  float den = 0.f;
  float acc[16];
#pragma unroll
  for (int j = 0; j < 16; ++j) acc[j] = 0.f;
  for (int e = o0; e < o1; ++e) {
    int s = csr_s[e];
    float ee = el_s[s][hd] + erd;
    ee = fmaxf(ee, 0.2f * ee);
    float p = __expf(ee);               // no max-shift: |e| bounded, exact alpha
    den += p;
    const float* fr = &feat[s * 68 + (hd << 4)];
#pragma unroll
    for (int c = 0; c < 4; ++c) {
      float4 fv = *(const float4*)&fr[c << 2];
      acc[c*4+0] = fmaf(p, fv.x, acc[c*4+0]);
      acc[c*4+1] = fmaf(p, fv.y, acc[c*4+1]);
      acc[c*4+2] = fmaf(p, fv.z, acc[c*4+2]);
      acc[c*4+3] = fmaf(p, fv.w, acc[c*4+3]);
    }
  }
  float inv = __builtin_amdgcn_rcpf(den);
  float* gp = g_out + (size_t)bt * 4096 + (d << 6) + (hd << 4);
#pragma unroll
  for (int c = 0; c < 4; ++c) {
    float4 o;
    o.x = acc[c*4+0] * inv; o.y = acc[c*4+1] * inv;
    o.z = acc[c*4+2] * inv; o.w = acc[c*4+3] * inv;
    *(float4*)&gp[c << 2] = o;
  }
}

// ---- k_gru: per (f,b); f16-dot2 matvecs (fp32 accum), g/h inputs packed ----
__device__ __forceinline__ float qsum(float v) {
  v += __int_as_float(__builtin_amdgcn_mov_dpp(__float_as_int(v), 0xB1, 0xF, 0xF, true));
  v += __int_as_float(__builtin_amdgcn_mov_dpp(__float_as_int(v), 0x4E, 0xF, 0xF, true));
  return v;
}

__global__ __launch_bounds__(256, 4) void k_gru(
    const float* __restrict__ W_ih, const float* __restrict__ W_hh,
    const float* __restrict__ b_ih, const float* __restrict__ b_hh,
    const float* __restrict__ W_dec, const float* __restrict__ b_dec,
    float* __restrict__ hid, float* __restrict__ ans) {
  __shared__ __align__(16) h2f g16[16][32];       // one group's g, f16 pairs (2 KB)
  __shared__ __align__(16) float4 xw4[16 * 64];   // [ts][row] {xr,xz,xn,-} (16 KB)
  __shared__ __align__(16) __fp16 h16[2][64];     // h state, f16 (256 B)
  __shared__ __align__(16) float hbuf[2][8][64];
  int blk = blockIdx.x;
  int f = blk & 63, b = blk >> 6;
  int t = threadIdx.x;
  int row = t >> 2, kg = t & 3;

  const float* Wi = W_ih + f * 12288 + (kg << 4);
  const float* Wh = W_hh + f * 12288 + (kg << 4);
  h2f wi0[8], wi1[8], wi2[8], wh0[8], wh1[8], wh2[8];
#pragma unroll
  for (int c = 0; c < 4; ++c) {
    float4 v;
    v = *(const float4*)(Wi + (row << 6)         + (c << 2));
    wi0[c*2] = pkh(v.x, v.y); wi0[c*2+1] = pkh(v.z, v.w);
    v = *(const float4*)(Wi + ((64 + row) << 6)  + (c << 2));
    wi1[c*2] = pkh(v.x, v.y); wi1[c*2+1] = pkh(v.z, v.w);
    v = *(const float4*)(Wi + ((128 + row) << 6) + (c << 2));
    wi2[c*2] = pkh(v.x, v.y); wi2[c*2+1] = pkh(v.z, v.w);
    v = *(const float4*)(Wh + (row << 6)         + (c << 2));
    wh0[c*2] = pkh(v.x, v.y); wh0[c*2+1] = pkh(v.z, v.w);
    v = *(const float4*)(Wh + ((64 + row) << 6)  + (c << 2));
    wh1[c*2] = pkh(v.x, v.y); wh1[c*2+1] = pkh(v.z, v.w);
    v = *(const float4*)(Wh + ((128 + row) << 6) + (c << 2));
    wh2[c*2] = pkh(v.x, v.y); wh2[c*2+1] = pkh(v.z, v.w);
  }
  float bR  = b_ih[f*192 + row]       + b_hh[f*192 + row];
  float bZ  = b_ih[f*192 + 64 + row]  + b_hh[f*192 + 64 + row];
  float bXN = b_ih[f*192 + 128 + row];
  float bHN = b_hh[f*192 + 128 + row];
  int j2 = t & 31;
  float wd0 = W_dec[(f << 6) + j2], wd1 = W_dec[(f << 6) + 32 + j2];
  float bdec = b_dec[f];
  size_t hidbase = (size_t)b * 262144 + (f << 6);   // hid[b][ts][f][:]
  float hreg = 0.f;
  if (t < 64) { h16[0][t] = (__fp16)0.f; h16[1][t] = (__fp16)0.f; }
  __syncthreads();

#pragma unroll 1
  for (int G = 0; G < 4; ++G) {
    // ---- stage this group's g as f16 pairs (own column, in-place safe) ----
    {
      int i = t >> 4, ch = t & 15;
      float4 v = *(const float4*)&hid[hidbase + (size_t)((G << 4) + i) * 4096 + (ch << 2)];
      g16[i][(ch << 1)]     = pkh(v.x, v.y);
      g16[i][(ch << 1) + 1] = pkh(v.z, v.w);
    }
    __syncthreads();

    // ---- phase A: xw via fdot2 (8 dot2/gate); g-row read once per ts ----
#pragma unroll
    for (int ts = 0; ts < 16; ++ts) {
      const h2f* gp = &g16[ts][kg << 3];
      h2f gv[8];
#pragma unroll
      for (int j = 0; j < 8; ++j) gv[j] = gp[j];
      float p0 = 0.f, p1 = 0.f, p2 = 0.f;
#pragma unroll
      for (int j = 0; j < 8; ++j) {
        p0 = __builtin_amdgcn_fdot2(gv[j], wi0[j], p0, false);
        p1 = __builtin_amdgcn_fdot2(gv[j], wi1[j], p1, false);
        p2 = __builtin_amdgcn_fdot2(gv[j], wi2[j], p2, false);
      }
      p0 = qsum(p0); p1 = qsum(p1); p2 = qsum(p2);
      if (kg == 0) {                   // wave-private rows: no barrier needed
        float4 o; o.x = p0; o.y = p1; o.z = p2; o.w = 0.f;
        xw4[(ts << 6) + row] = o;
      }
    }

    // ---- 16 serial GRU steps (fully unrolled, static indices) ----
#pragma unroll
    for (int st = 0; st < 16; ++st) {
      const int cur = st & 1;
      float4 xg = xw4[(st << 6) + row];
      const h2f* hp = (const h2f*)&h16[cur][kg << 4];
      h2f hv[8];
#pragma unroll
      for (int j = 0; j < 8; ++j) hv[j] = hp[j];
      float pr = 0.f, pz = 0.f, pn = 0.f;
#pragma unroll
      for (int j = 0; j < 8; ++j) {
        pr = __builtin_amdgcn_fdot2(hv[j], wh0[j], pr, false);
        pz = __builtin_amdgcn_fdot2(hv[j], wh1[j], pz, false);
        pn = __builtin_amdgcn_fdot2(hv[j], wh2[j], pn, false);
      }
      pr = qsum(pr); pz = qsum(pz); pn = qsum(pn);
      float rr = __builtin_amdgcn_rcpf(1.f + __expf(-(pr + xg.x + bR)));
      float zz = __builtin_amdgcn_rcpf(1.f + __expf(-(pz + xg.y + bZ)));
      float pre = fmaf(rr, pn + bHN, xg.z + bXN);
      float nn = 1.f - 2.f * __builtin_amdgcn_rcpf(1.f + __expf(2.f * pre));
      float hnew = fmaf(zz, hreg - nn, nn);
      hreg = hnew;
      if (kg == 0) h16[cur ^ 1][row] = (__fp16)hnew;
      if (kg == 1) hbuf[(st >> 3) & 1][st & 7][row] = hnew;
      __syncthreads();
      if ((st & 7) == 7) {                  // flush 8 h-rows + fused decode
        const int gsel = (st >> 3) & 1;
        int ts0 = (G << 4) + st - 7;
        if (t < 128) {
          int i = t >> 4, j = t & 15;
          float4 hv4 = *(const float4*)&hbuf[gsel][i][j << 2];
          *(float4*)&hid[hidbase + (size_t)(ts0 + i) * 4096 + (j << 2)] = hv4;
        }
        int i2 = t >> 5;
        float part = hbuf[gsel][i2][j2] * wd0 + hbuf[gsel][i2][j2 + 32] * wd1;
        part += __shfl_xor(part, 1);  part += __shfl_xor(part, 2);
        part += __shfl_xor(part, 4);  part += __shfl_xor(part, 8);
        part += __shfl_xor(part, 16);
        if (j2 == 0) ans[((b << 6) + ts0 + i2) * 64 + f] = part + bdec;
      }
    }
  }
}

extern "C" void kernel_launch(void* const* d_in, const int* in_sizes, int n_in,
                              void* d_out, int out_size, void* d_ws, size_t ws_size,
                              hipStream_t stream) {
  const float* hist   = (const float*)d_in[0];
  const int* src      = (const int*)d_in[1];
  const int* dst      = (const int*)d_in[2];
  const float* W_enc  = (const float*)d_in[3];
  const float* b_enc  = (const float*)d_in[4];
  const float* W_gat  = (const float*)d_in[5];
  const float* attn_l = (const float*)d_in[6];
  const float* attn_r = (const float*)d_in[7];
  const float* b_gat  = (const float*)d_in[8];
  const float* W_ih   = (const float*)d_in[9];
  const float* W_hh   = (const float*)d_in[10];
  const float* b_ih   = (const float*)d_in[11];
  const float* b_hh   = (const float*)d_in[12];
  const float* W_dec  = (const float*)d_in[13];
  const float* b_dec  = (const float*)d_in[14];
  int E = in_sizes[1];

  float* ans = (float*)d_out;
  float* hid = (float*)d_out + Bb * Tt * Ff;   // [B,T,F,H]; holds g then h

  int* off   = (int*)d_ws;                     // 65 used (reserve 256)
  int* csr   = off + 256;                      // E used (reserve 2048)
  float* A   = (float*)(csr + 2048);           // 4096
  float* Bc  = A + 4096;                       // 4096 (b_gat folded)
  float* aA  = Bc + 4096;                      // 256
  float* aB  = aA + 256;
  float* rA  = aB + 256;
  float* rB  = rA + 256;

  hipLaunchKernelGGL(kprep, dim3(2), dim3(256), 0, stream,
                     src, dst, E, W_enc, b_enc, W_gat, attn_l, attn_r, b_gat,
                     off, csr, A, Bc, aA, aB, rA, rB);
  hipLaunchKernelGGL(k_gat, dim3(Bb * Tt), dim3(256), 0, stream,
                     hist, A, Bc, aA, aB, rA, rB, off, csr, E, hid);
  hipLaunchKernelGGL(k_gru, dim3(Ff * Bb), dim3(256), 0, stream,
                     W_ih, W_hh, b_ih, b_hh, W_dec, b_dec, hid, ans);
}

// Round 17
// 94.519 us; speedup vs baseline: 2.5514x; 1.4466x over previous
//
#include <hip/hip_runtime.h>
#include <hip/hip_bf16.h>
#include <math.h>

#define Bb 16
#define Tt 64
#define Ff 64
#define MAXE 2048

typedef __fp16 h2f __attribute__((ext_vector_type(2)));
__device__ __forceinline__ h2f pkh(float a, float b) {
  return __builtin_amdgcn_cvt_pkrtz(a, b);
}

// ---------------- kprep: block 0 = CSR build; block 1 = weight tables -------
__global__ __launch_bounds__(256) void kprep(
    const int* __restrict__ src, const int* __restrict__ dst, int E,
    const float* __restrict__ W_enc, const float* __restrict__ b_enc,
    const float* __restrict__ W_gat, const float* __restrict__ attn_l,
    const float* __restrict__ attn_r, const float* __restrict__ b_gat,
    int* __restrict__ off, int* __restrict__ csr,
    float* __restrict__ A, float* __restrict__ Bc,
    float* __restrict__ aA, float* __restrict__ aB,
    float* __restrict__ rA, float* __restrict__ rB) {
  __shared__ int s_src[MAXE], s_dst[MAXE];
  __shared__ int cnt[Ff], base[Ff];
  __shared__ __align__(16) float We[64][64], Be[64][64], Wg[64][64];
  __shared__ __align__(16) float As[64][64], Bs[64][64];
  __shared__ float al_s[64], ar_s[64], bg_s[64];
  int t = threadIdx.x;

  if (blockIdx.x == 0) {                       // ---- CSR by dst ----
    for (int e = t; e < E; e += 256) { s_src[e] = src[e]; s_dst[e] = dst[e]; }
    if (t < Ff) cnt[t] = 0;
    __syncthreads();
    for (int e = t; e < E; e += 256) atomicAdd(&cnt[s_dst[e]], 1);
    __syncthreads();
    if (t < 64) {
      // exclusive scan of 64 counts via wave shfl_up (6 steps)
      int c = cnt[t];
      int inc = c;
#pragma unroll
      for (int ofs = 1; ofs < 64; ofs <<= 1) {
        int up = __shfl_up(inc, ofs, 64);
        if (t >= ofs) inc += up;
      }
      int exc = inc - c;
      off[t] = exc;
      base[t] = exc;                 // base[] doubles as running cursor
      if (t == 63) off[64] = inc;
      // ballot-rank stable counting sort: 64 edges/chunk, e-ascending order
      for (int chunk = 0; chunk < E; chunk += 64) {
        int e = chunk + t;
        bool valid = e < E;
        int di = valid ? s_dst[e] : 64;        // sentinel group (bit 6)
        unsigned long long m = ~0ull;
#pragma unroll
        for (int bnum = 0; bnum < 7; ++bnum) {
          unsigned long long bb = __ballot((di >> bnum) & 1);
          m &= ((di >> bnum) & 1) ? bb : ~bb;
        }
        unsigned long long below = m & ((1ull << t) - 1ull);
        int rank = __popcll(below);
        if (valid) {
          int slot = base[di] + rank;
          csr[slot] = s_src[e];
          if (below == 0ull) base[di] += __popcll(m);  // group leader advances
        }
      }
    }
    return;
  }

  // ---- tables: A = We@Wg, Bc = Be@Wg (+b_gat), attn scalar tables ----
  for (int i = t; i < 1024; i += 256) {
    ((float4*)We)[i] = ((const float4*)W_enc)[i];
    ((float4*)Be)[i] = ((const float4*)b_enc)[i];
    ((float4*)Wg)[i] = ((const float4*)W_gat)[i];
  }
  if (t < 64) { al_s[t] = attn_l[t]; ar_s[t] = attn_r[t]; bg_s[t] = b_gat[t]; }
  __syncthreads();
  int n = t >> 2, q = t & 3;
  float accA[16], accB[16];
#pragma unroll
  for (int j = 0; j < 16; ++j) { accA[j] = 0.f; accB[j] = 0.f; }
  for (int k = 0; k < 64; ++k) {
    float we = We[n][k], be = Be[n][k];
#pragma unroll
    for (int c = 0; c < 4; ++c) {
      float4 wg = *(const float4*)&Wg[k][q * 16 + c * 4];
      accA[c*4+0] = fmaf(we, wg.x, accA[c*4+0]); accB[c*4+0] = fmaf(be, wg.x, accB[c*4+0]);
      accA[c*4+1] = fmaf(we, wg.y, accA[c*4+1]); accB[c*4+1] = fmaf(be, wg.y, accB[c*4+1]);
      accA[c*4+2] = fmaf(we, wg.z, accA[c*4+2]); accB[c*4+2] = fmaf(be, wg.z, accB[c*4+2]);
      accA[c*4+3] = fmaf(we, wg.w, accA[c*4+3]); accB[c*4+3] = fmaf(be, wg.w, accB[c*4+3]);
    }
  }
#pragma unroll
  for (int c = 0; c < 4; ++c) {
    float4 va, vb, vbg;
    va.x = accA[c*4+0]; va.y = accA[c*4+1]; va.z = accA[c*4+2]; va.w = accA[c*4+3];
    vb.x = accB[c*4+0]; vb.y = accB[c*4+1]; vb.z = accB[c*4+2]; vb.w = accB[c*4+3];
    vbg.x = vb.x + bg_s[q*16+c*4+0]; vbg.y = vb.y + bg_s[q*16+c*4+1];
    vbg.z = vb.z + bg_s[q*16+c*4+2]; vbg.w = vb.w + bg_s[q*16+c*4+3];
    *(float4*)&As[n][q*16 + c*4] = va;
    *(float4*)&Bs[n][q*16 + c*4] = vb;       // unfolded (attn tables)
    *(float4*)&A[n*64 + q*16 + c*4] = va;
    *(float4*)&Bc[n*64 + q*16 + c*4] = vbg;  // folded (+b_gat; sum(alpha)=1 => exact)
  }
  __syncthreads();
  float sa = 0.f, sb = 0.f, sra = 0.f, srb = 0.f;
#pragma unroll
  for (int j = 0; j < 16; ++j) {
    float alv = al_s[q*16 + j], arv = ar_s[q*16 + j];
    float av = As[n][q*16 + j], bv = Bs[n][q*16 + j];
    sa  = fmaf(av, alv, sa);  sb  = fmaf(bv, alv, sb);
    sra = fmaf(av, arv, sra); srb = fmaf(bv, arv, srb);
  }
  aA[t] = sa; aB[t] = sb; rA[t] = sra; rB[t] = srb;
}

// ---------------- k_gat: per (b,t); feat staged in LDS once ----------------
__global__ __launch_bounds__(256) void k_gat(
    const float* __restrict__ hist, const float* __restrict__ Ag,
    const float* __restrict__ Bg, const float* __restrict__ aAg,
    const float* __restrict__ aBg, const float* __restrict__ rAg,
    const float* __restrict__ rBg, const int* __restrict__ off,
    const int* __restrict__ csr, int E, float* __restrict__ g_out) {
  __shared__ __align__(16) float feat[64 * 68];   // feat' = x*A + Bc (padded rows)
  __shared__ float x_s[64];
  __shared__ float el_s[64][4], er_s[64][4];
  __shared__ int csr_s[1152];
  __shared__ int off_s[Ff + 1];
  int bt = blockIdx.x, t = threadIdx.x;
  if (t < 64) x_s[t] = hist[bt * 64 + t];
  if (t < Ff + 1) off_s[t] = off[t];
  for (int e = t; e < E; e += 256) csr_s[e] = csr[e];
  __syncthreads();

  // ---- stage feat: thread (s, q) -> feat[s][q*16..+15]; coalesced A/Bc ----
  int s0 = t >> 2, q = t & 3;
  {
    float xs = x_s[s0];
    const float4* Ar = (const float4*)(Ag + (s0 << 6) + (q << 4));
    const float4* Br = (const float4*)(Bg + (s0 << 6) + (q << 4));
#pragma unroll
    for (int c = 0; c < 4; ++c) {
      float4 a4 = Ar[c], b4 = Br[c];
      float4 o;
      o.x = fmaf(xs, a4.x, b4.x); o.y = fmaf(xs, a4.y, b4.y);
      o.z = fmaf(xs, a4.z, b4.z); o.w = fmaf(xs, a4.w, b4.w);
      *(float4*)&feat[s0 * 68 + (q << 4) + (c << 2)] = o;
    }
    el_s[s0][q] = fmaf(xs, aAg[t], aBg[t]);
    er_s[s0][q] = fmaf(xs, rAg[t], rBg[t]);
  }
  __syncthreads();

  // ---- edge phase: thread (d, hd); feat from LDS ----
  int d = s0, hd = q;
  int o0 = off_s[d], o1 = off_s[d + 1];
  float erd = er_s[d][hd];
  float den = 0.f;
  float acc[16];
#pragma unroll
  for (int j = 0; j < 16; ++j) acc[j] = 0.f;
  for (int e = o0; e < o1; ++e) {
    int s = csr_s[e];
    float ee = el_s[s][hd] + erd;
    ee = fmaxf(ee, 0.2f * ee);
    float p = __expf(ee);               // no max-shift: |e| bounded, exact alpha
    den += p;
    const float* fr = &feat[s * 68 + (hd << 4)];
#pragma unroll
    for (int c = 0; c < 4; ++c) {
      float4 fv = *(const float4*)&fr[c << 2];
      acc[c*4+0] = fmaf(p, fv.x, acc[c*4+0]);
      acc[c*4+1] = fmaf(p, fv.y, acc[c*4+1]);
      acc[c*4+2] = fmaf(p, fv.z, acc[c*4+2]);
      acc[c*4+3] = fmaf(p, fv.w, acc[c*4+3]);
    }
  }
  float inv = __builtin_amdgcn_rcpf(den);
  float* gp = g_out + (size_t)bt * 4096 + (d << 6) + (hd << 4);
#pragma unroll
  for (int c = 0; c < 4; ++c) {
    float4 o;
    o.x = acc[c*4+0] * inv; o.y = acc[c*4+1] * inv;
    o.z = acc[c*4+2] * inv; o.w = acc[c*4+3] * inv;
    *(float4*)&gp[c << 2] = o;
  }
}

// ---- k_gru: per (f,b); f16-dot2 matvecs (fp32 accum), g/h inputs packed ----
__device__ __forceinline__ float qsum(float v) {
  v += __int_as_float(__builtin_amdgcn_mov_dpp(__float_as_int(v), 0xB1, 0xF, 0xF, true));
  v += __int_as_float(__builtin_amdgcn_mov_dpp(__float_as_int(v), 0x4E, 0xF, 0xF, true));
  return v;
}

__global__ __launch_bounds__(256, 4) void k_gru(
    const float* __restrict__ W_ih, const float* __restrict__ W_hh,
    const float* __restrict__ b_ih, const float* __restrict__ b_hh,
    const float* __restrict__ W_dec, const float* __restrict__ b_dec,
    float* __restrict__ hid, float* __restrict__ ans) {
  __shared__ __align__(16) h2f g16[16][32];       // one group's g, f16 pairs (2 KB)
  __shared__ __align__(16) float4 xw4[16 * 64];   // [ts][row] {xr,xz,xn,-} (16 KB)
  __shared__ __align__(16) __fp16 h16[2][64];     // h state, f16 (256 B)
  __shared__ __align__(16) float hbuf[2][8][64];
  int blk = blockIdx.x;
  int f = blk & 63, b = blk >> 6;
  int t = threadIdx.x;
  int row = t >> 2, kg = t & 3;

  const float* Wi = W_ih + f * 12288 + (kg << 4);
  const float* Wh = W_hh + f * 12288 + (kg << 4);
  h2f wi0[8], wi1[8], wi2[8], wh0[8], wh1[8], wh2[8];
#pragma unroll
  for (int c = 0; c < 4; ++c) {
    float4 v;
    v = *(const float4*)(Wi + (row << 6)         + (c << 2));
    wi0[c*2] = pkh(v.x, v.y); wi0[c*2+1] = pkh(v.z, v.w);
    v = *(const float4*)(Wi + ((64 + row) << 6)  + (c << 2));
    wi1[c*2] = pkh(v.x, v.y); wi1[c*2+1] = pkh(v.z, v.w);
    v = *(const float4*)(Wi + ((128 + row) << 6) + (c << 2));
    wi2[c*2] = pkh(v.x, v.y); wi2[c*2+1] = pkh(v.z, v.w);
    v = *(const float4*)(Wh + (row << 6)         + (c << 2));
    wh0[c*2] = pkh(v.x, v.y); wh0[c*2+1] = pkh(v.z, v.w);
    v = *(const float4*)(Wh + ((64 + row) << 6)  + (c << 2));
    wh1[c*2] = pkh(v.x, v.y); wh1[c*2+1] = pkh(v.z, v.w);
    v = *(const float4*)(Wh + ((128 + row) << 6) + (c << 2));
    wh2[c*2] = pkh(v.x, v.y); wh2[c*2+1] = pkh(v.z, v.w);
  }
  float bR  = b_ih[f*192 + row]       + b_hh[f*192 + row];
  float bZ  = b_ih[f*192 + 64 + row]  + b_hh[f*192 + 64 + row];
  float bXN = b_ih[f*192 + 128 + row];
  float bHN = b_hh[f*192 + 128 + row];
  int j2 = t & 31;
  float wd0 = W_dec[(f << 6) + j2], wd1 = W_dec[(f << 6) + 32 + j2];
  float bdec = b_dec[f];
  size_t hidbase = (size_t)b * 262144 + (f << 6);   // hid[b][ts][f][:]
  float hreg = 0.f;
  if (t < 64) { h16[0][t] = (__fp16)0.f; h16[1][t] = (__fp16)0.f; }
  __syncthreads();

#pragma unroll 1
  for (int G = 0; G < 4; ++G) {
    // ---- stage this group's g as f16 pairs (own column, in-place safe) ----
    {
      int i = t >> 4, ch = t & 15;
      float4 v = *(const float4*)&hid[hidbase + (size_t)((G << 4) + i) * 4096 + (ch << 2)];
      g16[i][(ch << 1)]     = pkh(v.x, v.y);
      g16[i][(ch << 1) + 1] = pkh(v.z, v.w);
    }
    __syncthreads();

    // ---- phase A: xw via fdot2 (8 dot2/gate); g-row read once per ts ----
#pragma unroll
    for (int ts = 0; ts < 16; ++ts) {
      const h2f* gp = &g16[ts][kg << 3];
      h2f gv[8];
#pragma unroll
      for (int j = 0; j < 8; ++j) gv[j] = gp[j];
      float p0 = 0.f, p1 = 0.f, p2 = 0.f;
#pragma unroll
      for (int j = 0; j < 8; ++j) {
        p0 = __builtin_amdgcn_fdot2(gv[j], wi0[j], p0, false);
        p1 = __builtin_amdgcn_fdot2(gv[j], wi1[j], p1, false);
        p2 = __builtin_amdgcn_fdot2(gv[j], wi2[j], p2, false);
      }
      p0 = qsum(p0); p1 = qsum(p1); p2 = qsum(p2);
      if (kg == 0) {                   // wave-private rows: no barrier needed
        float4 o; o.x = p0; o.y = p1; o.z = p2; o.w = 0.f;
        xw4[(ts << 6) + row] = o;
      }
    }

    // ---- 16 serial GRU steps (fully unrolled, static indices) ----
#pragma unroll
    for (int st = 0; st < 16; ++st) {
      const int cur = st & 1;
      float4 xg = xw4[(st << 6) + row];
      const h2f* hp = (const h2f*)&h16[cur][kg << 4];
      h2f hv[8];
#pragma unroll
      for (int j = 0; j < 8; ++j) hv[j] = hp[j];
      float pr = 0.f, pz = 0.f, pn = 0.f;
#pragma unroll
      for (int j = 0; j < 8; ++j) {
        pr = __builtin_amdgcn_fdot2(hv[j], wh0[j], pr, false);
        pz = __builtin_amdgcn_fdot2(hv[j], wh1[j], pz, false);
        pn = __builtin_amdgcn_fdot2(hv[j], wh2[j], pn, false);
      }
      pr = qsum(pr); pz = qsum(pz); pn = qsum(pn);
      float rr = __builtin_amdgcn_rcpf(1.f + __expf(-(pr + xg.x + bR)));
      float zz = __builtin_amdgcn_rcpf(1.f + __expf(-(pz + xg.y + bZ)));
      float pre = fmaf(rr, pn + bHN, xg.z + bXN);
      float nn = 1.f - 2.f * __builtin_amdgcn_rcpf(1.f + __expf(2.f * pre));
      float hnew = fmaf(zz, hreg - nn, nn);
      hreg = hnew;
      if (kg == 0) h16[cur ^ 1][row] = (__fp16)hnew;
      if (kg == 1) hbuf[(st >> 3) & 1][st & 7][row] = hnew;
      __syncthreads();
      if ((st & 7) == 7) {                  // flush 8 h-rows + fused decode
        const int gsel = (st >> 3) & 1;
        int ts0 = (G << 4) + st - 7;
        if (t < 128) {
          int i = t >> 4, j = t & 15;
          float4 hv4 = *(const float4*)&hbuf[gsel][i][j << 2];
          *(float4*)&hid[hidbase + (size_t)(ts0 + i) * 4096 + (j << 2)] = hv4;
        }
        int i2 = t >> 5;
        float part = hbuf[gsel][i2][j2] * wd0 + hbuf[gsel][i2][j2 + 32] * wd1;
        part += __shfl_xor(part, 1);  part += __shfl_xor(part, 2);
        part += __shfl_xor(part, 4);  part += __shfl_xor(part, 8);
        part += __shfl_xor(part, 16);
        if (j2 == 0) ans[((b << 6) + ts0 + i2) * 64 + f] = part + bdec;
      }
    }
  }
}

extern "C" void kernel_launch(void* const* d_in, const int* in_sizes, int n_in,
                              void* d_out, int out_size, void* d_ws, size_t ws_size,
                              hipStream_t stream) {
  const float* hist   = (const float*)d_in[0];
  const int* src      = (const int*)d_in[1];
  const int* dst      = (const int*)d_in[2];
  const float* W_enc  = (const float*)d_in[3];
  const float* b_enc  = (const float*)d_in[4];
  const float* W_gat  = (const float*)d_in[5];
  const float* attn_l = (const float*)d_in[6];
  const float* attn_r = (const float*)d_in[7];
  const float* b_gat  = (const float*)d_in[8];
  const float* W_ih   = (const float*)d_in[9];
  const float* W_hh   = (const float*)d_in[10];
  const float* b_ih   = (const float*)d_in[11];
  const float* b_hh   = (const float*)d_in[12];
  const float* W_dec  = (const float*)d_in[13];
  const float* b_dec  = (const float*)d_in[14];
  int E = in_sizes[1];

  float* ans = (float*)d_out;
  float* hid = (float*)d_out + Bb * Tt * Ff;   // [B,T,F,H]; holds g then h

  int* off   = (int*)d_ws;                     // 65 used (reserve 256)
  int* csr   = off + 256;                      // E used (reserve 2048)
  float* A   = (float*)(csr + 2048);           // 4096
  float* Bc  = A + 4096;                       // 4096 (b_gat folded)
  float* aA  = Bc + 4096;                      // 256
  float* aB  = aA + 256;
  float* rA  = aB + 256;
  float* rB  = rA + 256;

  hipLaunchKernelGGL(kprep, dim3(2), dim3(256), 0, stream,
                     src, dst, E, W_enc, b_enc, W_gat, attn_l, attn_r, b_gat,
                     off, csr, A, Bc, aA, aB, rA, rB);
  hipLaunchKernelGGL(k_gat, dim3(Bb * Tt), dim3(256), 0, stream,
                     hist, A, Bc, aA, aB, rA, rB, off, csr, E, hid);
  hipLaunchKernelGGL(k_gru, dim3(Ff * Bb), dim3(256), 0, stream,
                     W_ih, W_hh, b_ih, b_hh, W_dec, b_dec, hid, ans);
}